// Round 3
// baseline (3641.891 us; speedup 1.0000x reference)
//
#include <hip/hip_runtime.h>
#include <hip/hip_bf16.h>
#include <cstddef>

// Problem constants
#define HW      512
#define CCH     16           // channels
#define KB11    11           // spline bases per channel
#define TILE    32           // output tile (32x32)
#define HALO    34           // input tile with 1-pixel halo
#define PSTR    12           // floats per pixel in LDS derived tile

// Derived values for one input value v:
//   d[0]    = silu(v)
//   d[1+k]  = cubic B-spline basis k (k=0..10) on grid g(i) = -1.75 + 0.25*i
__device__ __forceinline__ void compute_derived(float x, float* d) {
    d[0] = x / (1.0f + __expf(-x));           // silu
    float b0[14];
#pragma unroll
    for (int i = 0; i < 14; ++i) {
        float gl = -1.75f + 0.25f * i;
        float gr = gl + 0.25f;
        b0[i] = (x >= gl && x < gr) ? 1.0f : 0.0f;
    }
    float b1[13];
#pragma unroll
    for (int i = 0; i < 13; ++i) {
        float gi = -1.75f + 0.25f * i;
        b1[i] = (x - gi) * 4.0f * b0[i] + ((gi + 0.50f) - x) * 4.0f * b0[i + 1];
    }
    float b2[12];
#pragma unroll
    for (int i = 0; i < 12; ++i) {
        float gi = -1.75f + 0.25f * i;
        b2[i] = (x - gi) * 2.0f * b1[i] + ((gi + 0.75f) - x) * 2.0f * b1[i + 1];
    }
#pragma unroll
    for (int i = 0; i < 11; ++i) {
        float gi = -1.75f + 0.25f * i;
        d[1 + i] = (x - gi) * (4.0f / 3.0f) * b2[i]
                 + ((gi + 1.00f) - x) * (4.0f / 3.0f) * b2[i + 1];
    }
}

// Fused KAN conv layer (pre-norm output), plain input (transform pre-applied):
//   z[b,co,y,x] = sum_{ci,dy,dx,k} derived_k(in[b,ci,y+dy-1,x+dx-1]) * W[co,ci,k,dy,dx]
// bw: (16,16,3,3)  sw: (16,176,3,3)
// waves_per_eu(2,2): LDS (62.4KB) caps us at 2 blocks/CU = 2 waves/EU anyway;
// pinning max=2 gives the register allocator the full 256-VGPR budget so the
// acc[4][16]+v[4][12] working set stays in registers (round-2: VGPR=88 with
// scratch spills -> 4.37 GB of HBM writes per dispatch).
__global__ __attribute__((amdgpu_waves_per_eu(2, 2))) __launch_bounds__(256)
void conv_kan(
    const float* __restrict__ in,
    const float* __restrict__ bw,
    const float* __restrict__ sw,
    float* __restrict__ z)
{
    __shared__ float dtile[HALO * HALO * PSTR];   // 55488 B
    __shared__ float wtile[9 * 12 * 16];          // 6912 B   [tap][k][co]

    const int tid = threadIdx.x;
    const int tx = tid & 15;
    const int ty = tid >> 4;
    const int bx0 = blockIdx.x * TILE;
    const int by0 = blockIdx.y * TILE;
    const int b = blockIdx.z;

    float acc[4][16];
#pragma unroll
    for (int p = 0; p < 4; ++p)
#pragma unroll
        for (int c = 0; c < 16; ++c) acc[p][c] = 0.0f;

#pragma unroll 1
    for (int cin = 0; cin < CCH; ++cin) {
        __syncthreads();
        // ---- stage weights for this cin: wtile[tap][k][co] ----
        for (int e = tid; e < 1728; e += 256) {
            int tap = e / 192;
            int r = e - tap * 192;
            int k = r >> 4;
            int co = r & 15;
            float w = (k == 0) ? bw[(co * CCH + cin) * 9 + tap]
                               : sw[((size_t)co * (CCH * KB11) + cin * KB11 + (k - 1)) * 9 + tap];
            wtile[e] = w;
        }
        // ---- stage derived values for this input channel into LDS ----
        for (int idx = tid; idx < HALO * HALO; idx += 256) {
            int iy = idx / HALO;
            int ix = idx - iy * HALO;
            int gy = by0 + iy - 1;
            int gx = bx0 + ix - 1;
            float4 d0 = {0.f, 0.f, 0.f, 0.f};
            float4 d1 = {0.f, 0.f, 0.f, 0.f};
            float4 d2 = {0.f, 0.f, 0.f, 0.f};
            if ((unsigned)gy < (unsigned)HW && (unsigned)gx < (unsigned)HW) {
                float v = in[(((size_t)b * CCH + cin) << 18) + ((size_t)gy << 9) + gx];
                float d[12];
                compute_derived(v, d);
                d0 = make_float4(d[0], d[1], d[2], d[3]);
                d1 = make_float4(d[4], d[5], d[6], d[7]);
                d2 = make_float4(d[8], d[9], d[10], d[11]);
            }
            float* p = &dtile[idx * PSTR];
            *reinterpret_cast<float4*>(p)     = d0;
            *reinterpret_cast<float4*>(p + 4) = d1;
            *reinterpret_cast<float4*>(p + 8) = d2;
        }
        __syncthreads();

        // ---- accumulate: 4 pixels x 16 couts per thread ----
#pragma unroll 1
        for (int tap = 0; tap < 9; ++tap) {
            const int tdy = tap / 3;
            const int tdx = tap - tdy * 3;
            float v[4][12];
#pragma unroll
            for (int p = 0; p < 4; ++p) {
                int py = ty + ((p >> 1) << 4) + tdy;
                int px = tx + ((p & 1) << 4) + tdx;
                const float* s = &dtile[(py * HALO + px) * PSTR];
                float4 t0 = *reinterpret_cast<const float4*>(s);
                float4 t1 = *reinterpret_cast<const float4*>(s + 4);
                float4 t2 = *reinterpret_cast<const float4*>(s + 8);
                v[p][0] = t0.x; v[p][1] = t0.y; v[p][2]  = t0.z; v[p][3]  = t0.w;
                v[p][4] = t1.x; v[p][5] = t1.y; v[p][6]  = t1.z; v[p][7]  = t1.w;
                v[p][8] = t2.x; v[p][9] = t2.y; v[p][10] = t2.z; v[p][11] = t2.w;
            }
            const float* wp = &wtile[tap * 192];
#pragma unroll 4
            for (int k = 0; k < 12; ++k) {
                float4 w0 = *reinterpret_cast<const float4*>(&wp[k * 16 + 0]);
                float4 w1 = *reinterpret_cast<const float4*>(&wp[k * 16 + 4]);
                float4 w2 = *reinterpret_cast<const float4*>(&wp[k * 16 + 8]);
                float4 w3 = *reinterpret_cast<const float4*>(&wp[k * 16 + 12]);
#pragma unroll
                for (int p = 0; p < 4; ++p) {
                    float vv = v[p][k];
                    acc[p][0]  = fmaf(w0.x, vv, acc[p][0]);
                    acc[p][1]  = fmaf(w0.y, vv, acc[p][1]);
                    acc[p][2]  = fmaf(w0.z, vv, acc[p][2]);
                    acc[p][3]  = fmaf(w0.w, vv, acc[p][3]);
                    acc[p][4]  = fmaf(w1.x, vv, acc[p][4]);
                    acc[p][5]  = fmaf(w1.y, vv, acc[p][5]);
                    acc[p][6]  = fmaf(w1.z, vv, acc[p][6]);
                    acc[p][7]  = fmaf(w1.w, vv, acc[p][7]);
                    acc[p][8]  = fmaf(w2.x, vv, acc[p][8]);
                    acc[p][9]  = fmaf(w2.y, vv, acc[p][9]);
                    acc[p][10] = fmaf(w2.z, vv, acc[p][10]);
                    acc[p][11] = fmaf(w2.w, vv, acc[p][11]);
                    acc[p][12] = fmaf(w3.x, vv, acc[p][12]);
                    acc[p][13] = fmaf(w3.y, vv, acc[p][13]);
                    acc[p][14] = fmaf(w3.z, vv, acc[p][14]);
                    acc[p][15] = fmaf(w3.w, vv, acc[p][15]);
                }
            }
        }
    }

    // ---- write pre-norm z ----
#pragma unroll
    for (int p = 0; p < 4; ++p) {
        int gy = by0 + ty + ((p >> 1) << 4);
        int gx = bx0 + tx + ((p & 1) << 4);
#pragma unroll
        for (int co = 0; co < 16; ++co) {
            z[(((size_t)b * CCH + co) << 18) + ((size_t)gy << 9) + gx] = acc[p][co];
        }
    }
}

// Stage 1 of instance-norm reduction: per (bc, chunk) partial sum / sumsq.
// grid = (64 chunks, 64 bc), block = 256. Each block reduces 4096 elements.
__global__ void __launch_bounds__(256) reduce_partial(
    const float* __restrict__ z, float* __restrict__ part)
{
    const int bc = blockIdx.y;
    const float* p = z + ((size_t)bc << 18) + ((size_t)blockIdx.x << 12);
    float s = 0.0f, q = 0.0f;
    for (int i = threadIdx.x; i < 4096; i += 256) {
        float v = p[i];
        s += v;
        q = fmaf(v, v, q);
    }
#pragma unroll
    for (int off = 32; off > 0; off >>= 1) {
        s += __shfl_down(s, off);
        q += __shfl_down(q, off);
    }
    __shared__ float ls[4], lq[4];
    const int wid = threadIdx.x >> 6;
    if ((threadIdx.x & 63) == 0) { ls[wid] = s; lq[wid] = q; }
    __syncthreads();
    if (threadIdx.x == 0) {
        float S = ls[0] + ls[1] + ls[2] + ls[3];
        float Q = lq[0] + lq[1] + lq[2] + lq[3];
        part[((size_t)bc * 64 + blockIdx.x) * 2]     = S;
        part[((size_t)bc * 64 + blockIdx.x) * 2 + 1] = Q;
    }
}

// Stage 2: fold 64 partials per bc into (mean, rstd). 1 block of 64 threads.
__global__ void reduce_final(const float* __restrict__ part, float* __restrict__ stats)
{
    const int bc = threadIdx.x;   // 0..63
    float s = 0.0f, q = 0.0f;
    for (int i = 0; i < 64; ++i) {
        s += part[((size_t)bc * 64 + i) * 2];
        q += part[((size_t)bc * 64 + i) * 2 + 1];
    }
    const float inv = 1.0f / 262144.0f;
    float m = s * inv;
    float var = q * inv - m * m;
    stats[bc * 2]     = m;
    stats[bc * 2 + 1] = rsqrtf(var + 1e-5f);
}

// y = prelu(instancenorm(z)) in place, float4-wide. 16384 blocks x 256.
__global__ void __launch_bounds__(256) norm_prelu(
    float* __restrict__ y, const float* __restrict__ stats,
    const float* __restrict__ a_ptr)
{
    const float a = *a_ptr;
    const int i4 = blockIdx.x * 256 + threadIdx.x;
    const int bc = i4 >> 16;
    const float m = stats[bc * 2];
    const float r = stats[bc * 2 + 1];
    float4 v = reinterpret_cast<float4*>(y)[i4];
    float t;
    t = (v.x - m) * r; v.x = (t >= 0.f) ? t : a * t;
    t = (v.y - m) * r; v.y = (t >= 0.f) ? t : a * t;
    t = (v.z - m) * r; v.z = (t >= 0.f) ? t : a * t;
    t = (v.w - m) * r; v.w = (t >= 0.f) ? t : a * t;
    reinterpret_cast<float4*>(y)[i4] = v;
}

// Final: out = sigmoid(prelu(instancenorm(z2))) in place on d_out, float4-wide.
__global__ void __launch_bounds__(256) final_sigmoid(
    float* __restrict__ out, const float* __restrict__ stats,
    const float* __restrict__ a_ptr)
{
    const float a = *a_ptr;
    const int i4 = blockIdx.x * 256 + threadIdx.x;
    const int bc = i4 >> 16;
    const float m = stats[bc * 2];
    const float r = stats[bc * 2 + 1];
    float4 v = reinterpret_cast<float4*>(out)[i4];
    float t;
    t = (v.x - m) * r; t = (t >= 0.f) ? t : a * t; v.x = 1.0f / (1.0f + __expf(-t));
    t = (v.y - m) * r; t = (t >= 0.f) ? t : a * t; v.y = 1.0f / (1.0f + __expf(-t));
    t = (v.z - m) * r; t = (t >= 0.f) ? t : a * t; v.z = 1.0f / (1.0f + __expf(-t));
    t = (v.w - m) * r; t = (t >= 0.f) ? t : a * t; v.w = 1.0f / (1.0f + __expf(-t));
    reinterpret_cast<float4*>(out)[i4] = v;
}

extern "C" void kernel_launch(void* const* d_in, const int* in_sizes, int n_in,
                              void* d_out, int out_size, void* d_ws, size_t ws_size,
                              hipStream_t stream)
{
    const float* x        = (const float*)d_in[0];
    const float* base_w1  = (const float*)d_in[1];
    const float* spline_w1= (const float*)d_in[2];
    const float* prelu_a1 = (const float*)d_in[3];
    const float* base_w2  = (const float*)d_in[4];
    const float* spline_w2= (const float*)d_in[5];
    const float* prelu_a2 = (const float*)d_in[6];
    float* out_f = (float*)d_out;
    float* ws_f  = (float*)d_ws;

    // Buffer plan — NOTHING outside ws[0,64MiB) and d_out[0,64MiB):
    //   z1/y1   : ws_f[0 .. 16.78M)                (64 MiB)
    //   part1   : out_f[0 .. 8192)                 (d_out free until conv2)
    //   stats1  : out_f[8192 .. 8320)
    //   z2      : out_f[0 .. 16.78M)               (overwrites dead part1/stats1)
    //   part2   : ws_f[0 .. 8192)                  (y1 dead after conv2)
    //   stats2  : ws_f[8192 .. 8320)
    float* z1     = ws_f;
    float* part1  = out_f;
    float* stats1 = out_f + 8192;
    float* part2  = ws_f;
    float* stats2 = ws_f + 8192;

    dim3 cgrid(HW / TILE, HW / TILE, 4);   // (16,16,4)
    dim3 cblk(256);
    dim3 rgrid(64, 64);
    dim3 egrid(16384);                     // elementwise float4 grid

    // ---- layer 1 ----
    conv_kan<<<cgrid, cblk, 0, stream>>>(x, base_w1, spline_w1, z1);
    reduce_partial<<<rgrid, cblk, 0, stream>>>(z1, part1);
    reduce_final<<<1, 64, 0, stream>>>(part1, stats1);
    norm_prelu<<<egrid, cblk, 0, stream>>>(z1, stats1, prelu_a1);   // z1 -> y1 in place

    // ---- layer 2 ----
    conv_kan<<<cgrid, cblk, 0, stream>>>(z1, base_w2, spline_w2, out_f);  // z2 -> d_out
    reduce_partial<<<rgrid, cblk, 0, stream>>>(out_f, part2);
    reduce_final<<<1, 64, 0, stream>>>(part2, stats2);

    // ---- final: norm + prelu + sigmoid, in place on d_out ----
    final_sigmoid<<<egrid, cblk, 0, stream>>>(out_f, stats2, prelu_a2);
}

// Round 4
// 1667.295 us; speedup vs baseline: 2.1843x; 2.1843x over previous
//
#include <hip/hip_runtime.h>
#include <hip/hip_bf16.h>
#include <cstddef>

// Problem constants
#define HW      512
#define CCH     16           // channels
#define KB11    11           // spline bases per channel
#define TILE    32           // output tile (32x32)
#define HALO    34           // input tile with 1-pixel halo
#define PSTR    12           // floats per pixel in LDS derived tile

// Derived values for one input value v:
//   d[0]    = silu(v)
//   d[1+k]  = cubic B-spline basis k (k=0..10) on grid g(i) = -1.75 + 0.25*i
__device__ __forceinline__ void compute_derived(float x, float* d) {
    d[0] = x / (1.0f + __expf(-x));           // silu
    float b0[14];
#pragma unroll
    for (int i = 0; i < 14; ++i) {
        float gl = -1.75f + 0.25f * i;
        float gr = gl + 0.25f;
        b0[i] = (x >= gl && x < gr) ? 1.0f : 0.0f;
    }
    float b1[13];
#pragma unroll
    for (int i = 0; i < 13; ++i) {
        float gi = -1.75f + 0.25f * i;
        b1[i] = (x - gi) * 4.0f * b0[i] + ((gi + 0.50f) - x) * 4.0f * b0[i + 1];
    }
    float b2[12];
#pragma unroll
    for (int i = 0; i < 12; ++i) {
        float gi = -1.75f + 0.25f * i;
        b2[i] = (x - gi) * 2.0f * b1[i] + ((gi + 0.75f) - x) * 2.0f * b1[i + 1];
    }
#pragma unroll
    for (int i = 0; i < 11; ++i) {
        float gi = -1.75f + 0.25f * i;
        d[1 + i] = (x - gi) * (4.0f / 3.0f) * b2[i]
                 + ((gi + 1.00f) - x) * (4.0f / 3.0f) * b2[i + 1];
    }
}

// Fused KAN conv layer (pre-norm output), plain input (transform pre-applied):
//   z[b,co,y,x] = sum_{ci,dy,dx,k} derived_k(in[b,ci,y+dy-1,x+dx-1]) * W[co,ci,k,dy,dx]
// bw: (16,16,3,3)  sw: (16,176,3,3)
// NOTE round-3 lesson: the k loop MUST be fully unrolled — any runtime k makes
// v[p][k] a runtime-indexed access, defeats SROA, and puts v[4][12] in scratch
// (measured: 4.4 GB HBM writes/dispatch, VGPR=88, VALUBusy 30%).
__global__ __attribute__((amdgpu_waves_per_eu(2, 2))) __launch_bounds__(256, 2)
void conv_kan(
    const float* __restrict__ in,
    const float* __restrict__ bw,
    const float* __restrict__ sw,
    float* __restrict__ z)
{
    __shared__ float dtile[HALO * HALO * PSTR];   // 55488 B
    __shared__ float wtile[9 * 12 * 16];          // 6912 B   [tap][k][co]

    const int tid = threadIdx.x;
    const int tx = tid & 15;
    const int ty = tid >> 4;
    const int bx0 = blockIdx.x * TILE;
    const int by0 = blockIdx.y * TILE;
    const int b = blockIdx.z;

    float acc[4][16];
#pragma unroll
    for (int p = 0; p < 4; ++p)
#pragma unroll
        for (int c = 0; c < 16; ++c) acc[p][c] = 0.0f;

#pragma unroll 1
    for (int cin = 0; cin < CCH; ++cin) {
        __syncthreads();
        // ---- stage weights for this cin: wtile[tap][k][co] ----
        for (int e = tid; e < 1728; e += 256) {
            int tap = e / 192;
            int r = e - tap * 192;
            int k = r >> 4;
            int co = r & 15;
            float w = (k == 0) ? bw[(co * CCH + cin) * 9 + tap]
                               : sw[((size_t)co * (CCH * KB11) + cin * KB11 + (k - 1)) * 9 + tap];
            wtile[e] = w;
        }
        // ---- stage derived values for this input channel into LDS ----
        for (int idx = tid; idx < HALO * HALO; idx += 256) {
            int iy = idx / HALO;
            int ix = idx - iy * HALO;
            int gy = by0 + iy - 1;
            int gx = bx0 + ix - 1;
            float4 d0 = {0.f, 0.f, 0.f, 0.f};
            float4 d1 = {0.f, 0.f, 0.f, 0.f};
            float4 d2 = {0.f, 0.f, 0.f, 0.f};
            if ((unsigned)gy < (unsigned)HW && (unsigned)gx < (unsigned)HW) {
                float v = in[(((size_t)b * CCH + cin) << 18) + ((size_t)gy << 9) + gx];
                float d[12];
                compute_derived(v, d);
                d0 = make_float4(d[0], d[1], d[2], d[3]);
                d1 = make_float4(d[4], d[5], d[6], d[7]);
                d2 = make_float4(d[8], d[9], d[10], d[11]);
            }
            float* p = &dtile[idx * PSTR];
            *reinterpret_cast<float4*>(p)     = d0;
            *reinterpret_cast<float4*>(p + 4) = d1;
            *reinterpret_cast<float4*>(p + 8) = d2;
        }
        __syncthreads();

        // ---- accumulate: 4 pixels x 16 couts per thread ----
#pragma unroll 1
        for (int tap = 0; tap < 9; ++tap) {
            const int tdy = tap / 3;
            const int tdx = tap - tdy * 3;
            float v[4][12];
#pragma unroll
            for (int p = 0; p < 4; ++p) {
                int py = ty + ((p >> 1) << 4) + tdy;
                int px = tx + ((p & 1) << 4) + tdx;
                const float* s = &dtile[(py * HALO + px) * PSTR];
                float4 t0 = *reinterpret_cast<const float4*>(s);
                float4 t1 = *reinterpret_cast<const float4*>(s + 4);
                float4 t2 = *reinterpret_cast<const float4*>(s + 8);
                v[p][0] = t0.x; v[p][1] = t0.y; v[p][2]  = t0.z; v[p][3]  = t0.w;
                v[p][4] = t1.x; v[p][5] = t1.y; v[p][6]  = t1.z; v[p][7]  = t1.w;
                v[p][8] = t2.x; v[p][9] = t2.y; v[p][10] = t2.z; v[p][11] = t2.w;
            }
            const float* wp = &wtile[tap * 192];
#pragma unroll   // FULL unroll — k must be compile-time so v[p][k] stays in regs
            for (int k = 0; k < 12; ++k) {
                float4 w0 = *reinterpret_cast<const float4*>(&wp[k * 16 + 0]);
                float4 w1 = *reinterpret_cast<const float4*>(&wp[k * 16 + 4]);
                float4 w2 = *reinterpret_cast<const float4*>(&wp[k * 16 + 8]);
                float4 w3 = *reinterpret_cast<const float4*>(&wp[k * 16 + 12]);
#pragma unroll
                for (int p = 0; p < 4; ++p) {
                    float vv = v[p][k];
                    acc[p][0]  = fmaf(w0.x, vv, acc[p][0]);
                    acc[p][1]  = fmaf(w0.y, vv, acc[p][1]);
                    acc[p][2]  = fmaf(w0.z, vv, acc[p][2]);
                    acc[p][3]  = fmaf(w0.w, vv, acc[p][3]);
                    acc[p][4]  = fmaf(w1.x, vv, acc[p][4]);
                    acc[p][5]  = fmaf(w1.y, vv, acc[p][5]);
                    acc[p][6]  = fmaf(w1.z, vv, acc[p][6]);
                    acc[p][7]  = fmaf(w1.w, vv, acc[p][7]);
                    acc[p][8]  = fmaf(w2.x, vv, acc[p][8]);
                    acc[p][9]  = fmaf(w2.y, vv, acc[p][9]);
                    acc[p][10] = fmaf(w2.z, vv, acc[p][10]);
                    acc[p][11] = fmaf(w2.w, vv, acc[p][11]);
                    acc[p][12] = fmaf(w3.x, vv, acc[p][12]);
                    acc[p][13] = fmaf(w3.y, vv, acc[p][13]);
                    acc[p][14] = fmaf(w3.z, vv, acc[p][14]);
                    acc[p][15] = fmaf(w3.w, vv, acc[p][15]);
                }
            }
        }
    }

    // ---- write pre-norm z ----
#pragma unroll
    for (int p = 0; p < 4; ++p) {
        int gy = by0 + ty + ((p >> 1) << 4);
        int gx = bx0 + tx + ((p & 1) << 4);
#pragma unroll
        for (int co = 0; co < 16; ++co) {
            z[(((size_t)b * CCH + co) << 18) + ((size_t)gy << 9) + gx] = acc[p][co];
        }
    }
}

// Stage 1 of instance-norm reduction: per (bc, chunk) partial sum / sumsq.
// grid = (64 chunks, 64 bc), block = 256. Each block reduces 4096 elements.
__global__ void __launch_bounds__(256) reduce_partial(
    const float* __restrict__ z, float* __restrict__ part)
{
    const int bc = blockIdx.y;
    const float* p = z + ((size_t)bc << 18) + ((size_t)blockIdx.x << 12);
    float s = 0.0f, q = 0.0f;
    for (int i = threadIdx.x; i < 4096; i += 256) {
        float v = p[i];
        s += v;
        q = fmaf(v, v, q);
    }
#pragma unroll
    for (int off = 32; off > 0; off >>= 1) {
        s += __shfl_down(s, off);
        q += __shfl_down(q, off);
    }
    __shared__ float ls[4], lq[4];
    const int wid = threadIdx.x >> 6;
    if ((threadIdx.x & 63) == 0) { ls[wid] = s; lq[wid] = q; }
    __syncthreads();
    if (threadIdx.x == 0) {
        float S = ls[0] + ls[1] + ls[2] + ls[3];
        float Q = lq[0] + lq[1] + lq[2] + lq[3];
        part[((size_t)bc * 64 + blockIdx.x) * 2]     = S;
        part[((size_t)bc * 64 + blockIdx.x) * 2 + 1] = Q;
    }
}

// Stage 2: fold 64 partials per bc into (mean, rstd). 1 block of 64 threads.
__global__ void reduce_final(const float* __restrict__ part, float* __restrict__ stats)
{
    const int bc = threadIdx.x;   // 0..63
    float s = 0.0f, q = 0.0f;
    for (int i = 0; i < 64; ++i) {
        s += part[((size_t)bc * 64 + i) * 2];
        q += part[((size_t)bc * 64 + i) * 2 + 1];
    }
    const float inv = 1.0f / 262144.0f;
    float m = s * inv;
    float var = q * inv - m * m;
    stats[bc * 2]     = m;
    stats[bc * 2 + 1] = rsqrtf(var + 1e-5f);
}

// y = prelu(instancenorm(z)) in place, float4-wide. 16384 blocks x 256.
__global__ void __launch_bounds__(256) norm_prelu(
    float* __restrict__ y, const float* __restrict__ stats,
    const float* __restrict__ a_ptr)
{
    const float a = *a_ptr;
    const int i4 = blockIdx.x * 256 + threadIdx.x;
    const int bc = i4 >> 16;
    const float m = stats[bc * 2];
    const float r = stats[bc * 2 + 1];
    float4 v = reinterpret_cast<float4*>(y)[i4];
    float t;
    t = (v.x - m) * r; v.x = (t >= 0.f) ? t : a * t;
    t = (v.y - m) * r; v.y = (t >= 0.f) ? t : a * t;
    t = (v.z - m) * r; v.z = (t >= 0.f) ? t : a * t;
    t = (v.w - m) * r; v.w = (t >= 0.f) ? t : a * t;
    reinterpret_cast<float4*>(y)[i4] = v;
}

// Final: out = sigmoid(prelu(instancenorm(z2))) in place on d_out, float4-wide.
__global__ void __launch_bounds__(256) final_sigmoid(
    float* __restrict__ out, const float* __restrict__ stats,
    const float* __restrict__ a_ptr)
{
    const float a = *a_ptr;
    const int i4 = blockIdx.x * 256 + threadIdx.x;
    const int bc = i4 >> 16;
    const float m = stats[bc * 2];
    const float r = stats[bc * 2 + 1];
    float4 v = reinterpret_cast<float4*>(out)[i4];
    float t;
    t = (v.x - m) * r; t = (t >= 0.f) ? t : a * t; v.x = 1.0f / (1.0f + __expf(-t));
    t = (v.y - m) * r; t = (t >= 0.f) ? t : a * t; v.y = 1.0f / (1.0f + __expf(-t));
    t = (v.z - m) * r; t = (t >= 0.f) ? t : a * t; v.z = 1.0f / (1.0f + __expf(-t));
    t = (v.w - m) * r; t = (t >= 0.f) ? t : a * t; v.w = 1.0f / (1.0f + __expf(-t));
    reinterpret_cast<float4*>(out)[i4] = v;
}

extern "C" void kernel_launch(void* const* d_in, const int* in_sizes, int n_in,
                              void* d_out, int out_size, void* d_ws, size_t ws_size,
                              hipStream_t stream)
{
    const float* x        = (const float*)d_in[0];
    const float* base_w1  = (const float*)d_in[1];
    const float* spline_w1= (const float*)d_in[2];
    const float* prelu_a1 = (const float*)d_in[3];
    const float* base_w2  = (const float*)d_in[4];
    const float* spline_w2= (const float*)d_in[5];
    const float* prelu_a2 = (const float*)d_in[6];
    float* out_f = (float*)d_out;
    float* ws_f  = (float*)d_ws;

    // Buffer plan — NOTHING outside ws[0,64MiB) and d_out[0,64MiB):
    //   z1/y1   : ws_f[0 .. 16.78M)                (64 MiB)
    //   part1   : out_f[0 .. 8192)                 (d_out free until conv2)
    //   stats1  : out_f[8192 .. 8320)
    //   z2      : out_f[0 .. 16.78M)               (overwrites dead part1/stats1)
    //   part2   : ws_f[0 .. 8192)                  (y1 dead after conv2)
    //   stats2  : ws_f[8192 .. 8320)
    float* z1     = ws_f;
    float* part1  = out_f;
    float* stats1 = out_f + 8192;
    float* part2  = ws_f;
    float* stats2 = ws_f + 8192;

    dim3 cgrid(HW / TILE, HW / TILE, 4);   // (16,16,4)
    dim3 cblk(256);
    dim3 rgrid(64, 64);
    dim3 egrid(16384);                     // elementwise float4 grid

    // ---- layer 1 ----
    conv_kan<<<cgrid, cblk, 0, stream>>>(x, base_w1, spline_w1, z1);
    reduce_partial<<<rgrid, cblk, 0, stream>>>(z1, part1);
    reduce_final<<<1, 64, 0, stream>>>(part1, stats1);
    norm_prelu<<<egrid, cblk, 0, stream>>>(z1, stats1, prelu_a1);   // z1 -> y1 in place

    // ---- layer 2 ----
    conv_kan<<<cgrid, cblk, 0, stream>>>(z1, base_w2, spline_w2, out_f);  // z2 -> d_out
    reduce_partial<<<rgrid, cblk, 0, stream>>>(out_f, part2);
    reduce_final<<<1, 64, 0, stream>>>(part2, stats2);

    // ---- final: norm + prelu + sigmoid, in place on d_out ----
    final_sigmoid<<<egrid, cblk, 0, stream>>>(out_f, stats2, prelu_a2);
}

// Round 5
// 606.252 us; speedup vs baseline: 6.0072x; 2.7502x over previous
//
#include <hip/hip_runtime.h>
#include <cstddef>

// ---------------- problem constants ----------------
#define HW   512
#define CCH  16
// conv tile: 16x16 output pixels per block, 18x18 halo
#define HTILE 18
#define NPIX  324          // 18*18
#define PIXW  48           // uints per halo pixel in LDS (96 f16 = 8 cins x 12 derived)

typedef _Float16 f16x8 __attribute__((ext_vector_type(8)));
typedef float    f32x4 __attribute__((ext_vector_type(4)));

__device__ __forceinline__ float h2f(ushort u) {
    _Float16 h = __builtin_bit_cast(_Float16, u);
    return (float)h;
}
__device__ __forceinline__ ushort f2h(float f) {
    _Float16 h = (_Float16)f;
    return __builtin_bit_cast(ushort, h);
}
__device__ __forceinline__ uint pack2h(float a, float b) {
    return (uint)f2h(a) | ((uint)f2h(b) << 16);
}

// Derived values for one input value v:
//   d[0]    = silu(v)
//   d[1+k]  = cubic B-spline basis k (k=0..10) on grid g(i) = -1.75 + 0.25*i
__device__ __forceinline__ void compute_derived(float x, float* d) {
    d[0] = x / (1.0f + __expf(-x));           // silu
    float b0[14];
#pragma unroll
    for (int i = 0; i < 14; ++i) {
        float gl = -1.75f + 0.25f * i;
        float gr = gl + 0.25f;
        b0[i] = (x >= gl && x < gr) ? 1.0f : 0.0f;
    }
    float b1[13];
#pragma unroll
    for (int i = 0; i < 13; ++i) {
        float gi = -1.75f + 0.25f * i;
        b1[i] = (x - gi) * 4.0f * b0[i] + ((gi + 0.50f) - x) * 4.0f * b0[i + 1];
    }
    float b2[12];
#pragma unroll
    for (int i = 0; i < 12; ++i) {
        float gi = -1.75f + 0.25f * i;
        b2[i] = (x - gi) * 2.0f * b1[i] + ((gi + 0.75f) - x) * 2.0f * b1[i + 1];
    }
#pragma unroll
    for (int i = 0; i < 11; ++i) {
        float gi = -1.75f + 0.25f * i;
        d[1 + i] = (x - gi) * (4.0f / 3.0f) * b2[i]
                 + ((gi + 1.00f) - x) * (4.0f / 3.0f) * b2[i + 1];
    }
}

// ---------------------------------------------------------------------------
// Weight prep: convert fp32 (bw, sw) into f16 MFMA A-operand fragment tables.
// Logical K index (per layer): chunk(2) x [ tap(9) * 96 + cin'(8)*12 + kv(12) ],
// 54 steps of 32. Fragment element j of lane l at step s = W[cout=l&15][k=32s+8q+j].
// Table: wtab[s*64 + lane] = uint4 (8 f16).
// ---------------------------------------------------------------------------
__global__ void __launch_bounds__(64) prep_w(
    const float* __restrict__ bw1, const float* __restrict__ sw1,
    const float* __restrict__ bw2, const float* __restrict__ sw2,
    uint4* __restrict__ wtab1, uint4* __restrict__ wtab2)
{
    const int s    = blockIdx.x;        // 0..53
    const int lane = threadIdx.x;       // 0..63
    const float* bw; const float* sw; uint4* wt;
    if (blockIdx.y == 0) { bw = bw1; sw = sw1; wt = wtab1; }
    else                 { bw = bw2; sw = sw2; wt = wtab2; }
    const int co = lane & 15, q = lane >> 4;
    const int chunk = s / 27, sl = s - chunk * 27;
    uint u[4];
#pragma unroll
    for (int jj = 0; jj < 4; ++jj) {
        float w[2];
#pragma unroll
        for (int h = 0; h < 2; ++h) {
            int j   = jj * 2 + h;
            int kl  = 32 * sl + 8 * q + j;     // k within chunk, 0..863
            int tap = kl / 96;
            int r   = kl - tap * 96;           // cin'*12 + kv
            int ci  = r / 12;
            int kv  = r - ci * 12;
            int cin = chunk * 8 + ci;
            w[h] = (kv == 0) ? bw[(co * 16 + cin) * 9 + tap]
                             : sw[(co * 176 + cin * 11 + (kv - 1)) * 9 + tap];
        }
        u[jj] = pack2h(w[0], w[1]);
    }
    wt[s * 64 + lane] = make_uint4(u[0], u[1], u[2], u[3]);
}

// ---------------------------------------------------------------------------
// Fused KAN conv layer via f16 MFMA implicit GEMM.
//   out[b,co,y,x] = sum_k W[co][k] * derived_k(in[b,...])   (pre-norm output)
// A = weights (register-resident frags), B = derived data (LDS), so D's
// col=lane&15 is the pixel -> coalesced stores.
// ---------------------------------------------------------------------------
template<bool IN_H, bool OUT_H>
__global__ __launch_bounds__(256, 2) void conv_mfma(
    const void* __restrict__ in_v,
    const uint4* __restrict__ wtab,
    void* __restrict__ out_v)
{
    __shared__ uint dtile[NPIX * PIXW];   // 62208 B

    const int tid  = threadIdx.x;
    const int lane = tid & 63;
    const int wv   = tid >> 6;            // wave 0..3
    const int m    = lane & 15;           // pixel-x within tile (B/D "n" index)
    const int q    = lane >> 4;           // k-octet selector
    const int bx0  = blockIdx.x * 16;
    const int by0  = blockIdx.y * 16;
    const int b    = blockIdx.z;

    const float*  inf = (const float*)in_v;
    const ushort* inh = (const ushort*)in_v;

    f32x4 acc[4];
#pragma unroll
    for (int t = 0; t < 4; ++t) acc[t] = f32x4{0.f, 0.f, 0.f, 0.f};

#pragma unroll 1
    for (int chunk = 0; chunk < 2; ++chunk) {
        __syncthreads();   // previous chunk's reads complete before overwrite
        // ---- stage derived f16 tile: items = (pix, cinpair) = 324*4 ----
        for (int it = tid; it < NPIX * 4; it += 256) {
            int cp  = it & 3;          // cin pair 0..3 -> cins 2cp, 2cp+1
            int pix = it >> 2;         // 0..323
            int py  = pix / 18;
            int px  = pix - py * 18;
            int gy  = by0 + py - 1;
            int gx  = bx0 + px - 1;
            uint u[12];
            bool ok = ((unsigned)gy < (unsigned)HW) && ((unsigned)gx < (unsigned)HW);
            if (ok) {
                size_t base = ((size_t)(b * CCH + chunk * 8 + cp * 2) << 18)
                            + ((size_t)gy << 9) + gx;
                float v0, v1;
                if (IN_H) { v0 = h2f(inh[base]); v1 = h2f(inh[base + (1u << 18)]); }
                else      { v0 = inf[base];      v1 = inf[base + (1u << 18)]; }
                float d0[12], d1[12];
                compute_derived(v0, d0);
                compute_derived(v1, d1);
                u[0]  = pack2h(d0[0], d0[1]);  u[1]  = pack2h(d0[2], d0[3]);
                u[2]  = pack2h(d0[4], d0[5]);  u[3]  = pack2h(d0[6], d0[7]);
                u[4]  = pack2h(d0[8], d0[9]);  u[5]  = pack2h(d0[10], d0[11]);
                u[6]  = pack2h(d1[0], d1[1]);  u[7]  = pack2h(d1[2], d1[3]);
                u[8]  = pack2h(d1[4], d1[5]);  u[9]  = pack2h(d1[6], d1[7]);
                u[10] = pack2h(d1[8], d1[9]);  u[11] = pack2h(d1[10], d1[11]);
            } else {
#pragma unroll
                for (int i = 0; i < 12; ++i) u[i] = 0u;  // zero-padded derived
            }
            uint off = (uint)pix * PIXW + (uint)cp * 12;
            *reinterpret_cast<uint4*>(&dtile[off + 0]) = make_uint4(u[0], u[1], u[2], u[3]);
            *reinterpret_cast<uint4*>(&dtile[off + 4]) = make_uint4(u[4], u[5], u[6], u[7]);
            *reinterpret_cast<uint4*>(&dtile[off + 8]) = make_uint4(u[8], u[9], u[10], u[11]);
        }
        __syncthreads();

        // ---- register-resident weight frags for this chunk ----
        uint4 wf[27];
#pragma unroll
        for (int s = 0; s < 27; ++s) wf[s] = wtab[(chunk * 27 + s) * 64 + lane];

        // ---- K loop: 27 steps x 4 pixel-row tiles ----
        const uint lanebase = (uint)m * PIXW + (uint)q * 4;
#pragma unroll
        for (int s = 0; s < 27; ++s) {
            const int tap = s / 3;
            const int tdy = tap / 3, tdx = tap - tdy * 3;
            const uint stepoff = (uint)(s - tap * 3) * 16;   // (s%3)*4 octets * 4 uints
#pragma unroll
            for (int t = 0; t < 4; ++t) {
                uint off = lanebase + stepoff
                         + (uint)(((wv * 4 + t + tdy) * 18 + tdx)) * PIXW;
                f16x8 a = *reinterpret_cast<const f16x8*>(&dtile[off]);
                acc[t] = __builtin_amdgcn_mfma_f32_16x16x32_f16(
                    __builtin_bit_cast(f16x8, wf[s]), a, acc[t], 0, 0, 0);
            }
        }
    }

    // ---- store: lane l reg r -> cout = 4q+r, px = m, row = wv*4+t ----
#pragma unroll
    for (int t = 0; t < 4; ++t) {
        int oy = by0 + wv * 4 + t;
#pragma unroll
        for (int r = 0; r < 4; ++r) {
            int co = q * 4 + r;
            size_t idx = ((size_t)(b * CCH + co) << 18) + ((size_t)oy << 9) + (bx0 + m);
            if (OUT_H) ((ushort*)out_v)[idx] = f2h(acc[t][r]);
            else       ((float*)out_v)[idx]  = acc[t][r];
        }
    }
}

// ---------------- instance-norm reductions ----------------
__global__ void __launch_bounds__(256) reduce_partial_h(
    const ushort* __restrict__ zh, float* __restrict__ part)
{
    const int bc = blockIdx.y;
    const uint* p = (const uint*)(zh + ((size_t)bc << 18) + ((size_t)blockIdx.x << 12));
    float s = 0.0f, qq = 0.0f;
    for (int i = threadIdx.x; i < 2048; i += 256) {
        uint u = p[i];
        float a = h2f((ushort)(u & 0xffffu));
        float c = h2f((ushort)(u >> 16));
        s += a + c;
        qq = fmaf(a, a, qq);
        qq = fmaf(c, c, qq);
    }
#pragma unroll
    for (int off = 32; off > 0; off >>= 1) {
        s  += __shfl_down(s, off);
        qq += __shfl_down(qq, off);
    }
    __shared__ float ls[4], lq[4];
    const int wid = threadIdx.x >> 6;
    if ((threadIdx.x & 63) == 0) { ls[wid] = s; lq[wid] = qq; }
    __syncthreads();
    if (threadIdx.x == 0) {
        part[((size_t)bc * 64 + blockIdx.x) * 2]     = ls[0] + ls[1] + ls[2] + ls[3];
        part[((size_t)bc * 64 + blockIdx.x) * 2 + 1] = lq[0] + lq[1] + lq[2] + lq[3];
    }
}

__global__ void __launch_bounds__(256) reduce_partial(
    const float* __restrict__ z, float* __restrict__ part)
{
    const int bc = blockIdx.y;
    const float* p = z + ((size_t)bc << 18) + ((size_t)blockIdx.x << 12);
    float s = 0.0f, qq = 0.0f;
    for (int i = threadIdx.x; i < 4096; i += 256) {
        float v = p[i];
        s += v;
        qq = fmaf(v, v, qq);
    }
#pragma unroll
    for (int off = 32; off > 0; off >>= 1) {
        s  += __shfl_down(s, off);
        qq += __shfl_down(qq, off);
    }
    __shared__ float ls[4], lq[4];
    const int wid = threadIdx.x >> 6;
    if ((threadIdx.x & 63) == 0) { ls[wid] = s; lq[wid] = qq; }
    __syncthreads();
    if (threadIdx.x == 0) {
        part[((size_t)bc * 64 + blockIdx.x) * 2]     = ls[0] + ls[1] + ls[2] + ls[3];
        part[((size_t)bc * 64 + blockIdx.x) * 2 + 1] = lq[0] + lq[1] + lq[2] + lq[3];
    }
}

__global__ void reduce_final(const float* __restrict__ part, float* __restrict__ stats)
{
    const int bc = threadIdx.x;   // 0..63
    float s = 0.0f, qq = 0.0f;
    for (int i = 0; i < 64; ++i) {
        s  += part[((size_t)bc * 64 + i) * 2];
        qq += part[((size_t)bc * 64 + i) * 2 + 1];
    }
    const float inv = 1.0f / 262144.0f;
    float mval = s * inv;
    float var  = qq * inv - mval * mval;
    stats[bc * 2]     = mval;
    stats[bc * 2 + 1] = rsqrtf(var + 1e-5f);
}

// y = prelu(instancenorm(z)) in place on f16 buffer; 1 uint2 (4 halves)/thread.
__global__ void __launch_bounds__(256) norm_prelu_h(
    ushort* __restrict__ y, const float* __restrict__ stats,
    const float* __restrict__ a_ptr)
{
    const float a = *a_ptr;
    const int i2 = blockIdx.x * 256 + threadIdx.x;   // 4194304 uint2 units
    const int bc = i2 >> 16;                         // 65536 units per bc
    const float mm = stats[bc * 2];
    const float rr = stats[bc * 2 + 1];
    uint2* py = (uint2*)y;
    uint2 v = py[i2];
    float f0 = h2f((ushort)(v.x & 0xffffu)), f1 = h2f((ushort)(v.x >> 16));
    float f2 = h2f((ushort)(v.y & 0xffffu)), f3 = h2f((ushort)(v.y >> 16));
    f0 = (f0 - mm) * rr; f0 = (f0 >= 0.f) ? f0 : a * f0;
    f1 = (f1 - mm) * rr; f1 = (f1 >= 0.f) ? f1 : a * f1;
    f2 = (f2 - mm) * rr; f2 = (f2 >= 0.f) ? f2 : a * f2;
    f3 = (f3 - mm) * rr; f3 = (f3 >= 0.f) ? f3 : a * f3;
    v.x = pack2h(f0, f1);
    v.y = pack2h(f2, f3);
    py[i2] = v;
}

// out = sigmoid(prelu(instancenorm(z2))) in place on d_out, float4-wide.
__global__ void __launch_bounds__(256) final_sigmoid(
    float* __restrict__ out, const float* __restrict__ stats,
    const float* __restrict__ a_ptr)
{
    const float a = *a_ptr;
    const int i4 = blockIdx.x * 256 + threadIdx.x;
    const int bc = i4 >> 16;
    const float mm = stats[bc * 2];
    const float rr = stats[bc * 2 + 1];
    float4 v = reinterpret_cast<float4*>(out)[i4];
    float t;
    t = (v.x - mm) * rr; t = (t >= 0.f) ? t : a * t; v.x = 1.0f / (1.0f + __expf(-t));
    t = (v.y - mm) * rr; t = (t >= 0.f) ? t : a * t; v.y = 1.0f / (1.0f + __expf(-t));
    t = (v.z - mm) * rr; t = (t >= 0.f) ? t : a * t; v.z = 1.0f / (1.0f + __expf(-t));
    t = (v.w - mm) * rr; t = (t >= 0.f) ? t : a * t; v.w = 1.0f / (1.0f + __expf(-t));
    reinterpret_cast<float4*>(out)[i4] = v;
}

extern "C" void kernel_launch(void* const* d_in, const int* in_sizes, int n_in,
                              void* d_out, int out_size, void* d_ws, size_t ws_size,
                              hipStream_t stream)
{
    const float* x        = (const float*)d_in[0];
    const float* base_w1  = (const float*)d_in[1];
    const float* spline_w1= (const float*)d_in[2];
    const float* prelu_a1 = (const float*)d_in[3];
    const float* base_w2  = (const float*)d_in[4];
    const float* spline_w2= (const float*)d_in[5];
    const float* prelu_a2 = (const float*)d_in[6];
    float* out_f = (float*)d_out;
    char*  wsb   = (char*)d_ws;

    // ws layout (all within 64 MiB):
    //   z1h    @ 0          : 4*16*512*512*2 = 33554432 B (f16, reused as y1h)
    //   wtab1  @ 33554432   : 54*64*16 = 55296 B
    //   wtab2  @ 33609728   : 55296 B
    //   part   @ 33665024   : 64*64*2*4 = 32768 B
    //   stats1 @ 33697792   : 512 B
    //   stats2 @ 33698304   : 512 B
    ushort* z1h    = (ushort*)wsb;
    uint4*  wtab1  = (uint4*)(wsb + 33554432);
    uint4*  wtab2  = (uint4*)(wsb + 33609728);
    float*  part   = (float*)(wsb + 33665024);
    float*  stats1 = (float*)(wsb + 33697792);
    float*  stats2 = (float*)(wsb + 33698304);

    dim3 cgrid(HW / 16, HW / 16, 4);   // (32,32,4)
    dim3 cblk(256);
    dim3 rgrid(64, 64);

    // weight tables for both layers
    prep_w<<<dim3(54, 2), 64, 0, stream>>>(base_w1, spline_w1, base_w2, spline_w2,
                                           wtab1, wtab2);

    // ---- layer 1: x (fp32) -> z1 (f16) ----
    conv_mfma<false, true><<<cgrid, cblk, 0, stream>>>(x, wtab1, z1h);
    reduce_partial_h<<<rgrid, cblk, 0, stream>>>(z1h, part);
    reduce_final<<<1, 64, 0, stream>>>(part, stats1);
    norm_prelu_h<<<16384, cblk, 0, stream>>>(z1h, stats1, prelu_a1);  // z1h -> y1h

    // ---- layer 2: y1 (f16) -> z2 (fp32, d_out) ----
    conv_mfma<true, false><<<cgrid, cblk, 0, stream>>>(z1h, wtab2, out_f);
    reduce_partial<<<rgrid, cblk, 0, stream>>>(out_f, part);
    reduce_final<<<1, 64, 0, stream>>>(part, stats2);

    // ---- final: norm + prelu + sigmoid in place on d_out ----
    final_sigmoid<<<16384, cblk, 0, stream>>>(out_f, stats2, prelu_a2);
}